// Round 5
// baseline (182.717 us; speedup 1.0000x reference)
//
#include <hip/hip_runtime.h>

// Segment-mean of subtoken embeddings (sorted segment ids) -> token embeddings.
//
// Phase 1 (table_kernel): flat lower-bound table over GLOBAL token ids
//   g = b*T + t; table[g] = first flat subtoken row s with global id >= g;
//   table[BT] = B*S. Each entry written exactly once.
// Phase 2 (seg_mean_kernel<NCH>): one WAVE per TPW consecutive tokens, whose
//   subtoken rows are one contiguous range [bnd[0], bnd[TPW]).
//   Rounds 1-3 all plateaued at ~60us / 2.1 TB/s with VGPR_Count 8-20:
//   the compiler emitted load->vmcnt(0)->add per row (~1 KB in flight/wave)
//   -> MLP starvation. This version issues RCHUNK*NCH independent dwordx4
//   loads into named registers before any use (12 KB in flight per wave),
//   then does boundary-aware accumulate/flush from the register file
//   (wave-uniform control flow). Nontemporal stores keep the 75 MB `out`
//   stream from evicting the L3-resident part of `hs`.
//   NOTE: NT-store builtin requires a NATIVE vector type (ext_vector_type),
//   not HIP's float4 struct — that was round 4's compile failure.

typedef float v4f __attribute__((ext_vector_type(4)));

#define TPW 4          // tokens per wave
#define WPB 4          // waves per block (256 threads)
#define TPB (TPW * WPB)
#define RCHUNK 4       // rows preloaded per inner iteration

__global__ void table_kernel(const int* __restrict__ seg,
                             const int* __restrict__ num_tokens_p,
                             int* __restrict__ table,
                             int BS_total,   // B*S
                             int BT) {       // B*T
  const int T = num_tokens_p[0];
  const int B = BT / T;
  const int S = BS_total / B;
  int s = blockIdx.x * blockDim.x + threadIdx.x;
  if (s >= BS_total) return;
  const int b = s / S;
  const int cur = b * T + seg[s];
  const int prev = (s == 0) ? -1 : ((s - 1) / S) * T + seg[s - 1];
  for (int g = prev + 1; g <= cur; ++g) table[g] = s;
  if (s == BS_total - 1) {
    for (int g = cur + 1; g <= BT; ++g) table[g] = BS_total;
  }
}

template <int NCH>
__global__ __launch_bounds__(WPB * 64) void seg_mean_kernel(
    const float* __restrict__ hs,      // [B*S, D] flat
    const int* __restrict__ table,     // [BT+1]
    float* __restrict__ out,           // [BT, D] flat
    int BT,
    int D4) {                          // D/4 (= NCH*64)
  const int lane = threadIdx.x & 63;
  const int wid = threadIdx.x >> 6;
  const int g0 = (blockIdx.x * WPB + wid) * TPW;
  if (g0 >= BT) return;
  const int ntok = min(TPW, BT - g0);

  int bnd[TPW + 1];
#pragma unroll
  for (int i = 0; i <= TPW; ++i)
    bnd[i] = table[g0 + ((i <= ntok) ? i : ntok)];  // pad -> empty tokens

  const v4f* __restrict__ hs4 = (const v4f*)hs;
  v4f* __restrict__ out4 = (v4f*)out;

  int r = bnd[0];
  const int rend = bnd[TPW];
  int tok = 0;

  v4f acc[NCH];
#pragma unroll
  for (int c = 0; c < NCH; ++c) acc[c] = (v4f)(0.f);

  // Flush any tokens whose range ends at/before position R (handles empty
  // tokens, including leading ones). acc is the running sum for token `tok`.
#define FLUSH_AT(R)                                                          \
  while (tok < TPW && bnd[tok + 1] <= (R)) {                                 \
    const int cnt = bnd[tok + 1] - bnd[tok];                                 \
    const float inv = (cnt > 0) ? (1.0f / (float)cnt) : 0.0f;                \
    if (tok < ntok) {                                                        \
      v4f* __restrict__ q = out4 + (size_t)(g0 + tok) * D4 + lane;           \
      _Pragma("unroll")                                                      \
      for (int c = 0; c < NCH; ++c) {                                        \
        v4f o = acc[c] * inv;                                                \
        __builtin_nontemporal_store(o, q + c * 64);                          \
      }                                                                      \
    }                                                                        \
    _Pragma("unroll")                                                        \
    for (int c = 0; c < NCH; ++c) acc[c] = (v4f)(0.f);                       \
    ++tok;                                                                   \
  }

  FLUSH_AT(r);  // leading empty tokens

  while (r < rend) {
    const int m = min(RCHUNK, rend - r);
    v4f v[RCHUNK][NCH];
    // Issue ALL loads for this chunk before any use: RCHUNK*NCH independent
    // dwordx4 loads in flight per wave.
#pragma unroll
    for (int j = 0; j < RCHUNK; ++j) {
      if (j < m) {
        const v4f* __restrict__ p = hs4 + (size_t)(r + j) * D4 + lane;
#pragma unroll
        for (int c = 0; c < NCH; ++c) v[j][c] = p[c * 64];
      }
    }
    // Accumulate + boundary flush from registers (uniform control flow).
#pragma unroll
    for (int j = 0; j < RCHUNK; ++j) {
      if (j < m) {
#pragma unroll
        for (int c = 0; c < NCH; ++c) acc[c] += v[j][c];
        FLUSH_AT(r + j + 1);
      }
    }
    r += m;
  }

  // Safety: anything not flushed (only possible when all remaining tokens are
  // empty with no rows at all) gets zeros.
  FLUSH_AT(rend);
  while (tok < TPW) {
    if (tok < ntok) {
      v4f* __restrict__ q = out4 + (size_t)(g0 + tok) * D4 + lane;
      const v4f z = (v4f)(0.f);
#pragma unroll
      for (int c = 0; c < NCH; ++c) __builtin_nontemporal_store(z, q + c * 64);
    }
    ++tok;
  }
#undef FLUSH_AT
}

// Generic fallback: one block per token, scalar loop over d. Only used if
// D is not a multiple of 256 (NCH path not applicable).
__global__ void seg_mean_fallback(const float* __restrict__ hs,
                                  const int* __restrict__ table,
                                  float* __restrict__ out,
                                  int D) {
  const int g = blockIdx.x;
  const int lo = table[g];
  const int hi = table[g + 1];
  const int cnt = hi - lo;
  const float inv = (cnt > 0) ? (1.0f / (float)cnt) : 0.0f;
  for (int d = threadIdx.x; d < D; d += blockDim.x) {
    float a = 0.f;
    for (int r = lo; r < hi; ++r) a += hs[(size_t)r * D + d];
    out[(size_t)g * D + d] = a * inv;
  }
}

extern "C" void kernel_launch(void* const* d_in, const int* in_sizes, int n_in,
                              void* d_out, int out_size, void* d_ws, size_t ws_size,
                              hipStream_t stream) {
  const float* hs = (const float*)d_in[0];
  const int* seg = (const int*)d_in[1];
  const int* num_tokens_p = (const int*)d_in[2];
  float* out = (float*)d_out;

  const int BS_total = in_sizes[1];            // B*S
  const int D = in_sizes[0] / in_sizes[1];     // 768
  const int BT = out_size / D;                 // B*T

  int* table = (int*)d_ws;                     // BT+1 ints

  const int threads1 = 256;
  const int grid1 = (BS_total + threads1 - 1) / threads1;
  hipLaunchKernelGGL(table_kernel, dim3(grid1), dim3(threads1), 0, stream,
                     seg, num_tokens_p, table, BS_total, BT);

  const int D4 = D / 4;
  const int grid2 = (BT + TPB - 1) / TPB;
  if (D % 4 == 0 && D4 % 64 == 0 && D4 / 64 >= 1 && D4 / 64 <= 4) {
    switch (D4 / 64) {
      case 1:
        hipLaunchKernelGGL(seg_mean_kernel<1>, dim3(grid2), dim3(WPB * 64), 0,
                           stream, hs, table, out, BT, D4);
        break;
      case 2:
        hipLaunchKernelGGL(seg_mean_kernel<2>, dim3(grid2), dim3(WPB * 64), 0,
                           stream, hs, table, out, BT, D4);
        break;
      case 3:
        hipLaunchKernelGGL(seg_mean_kernel<3>, dim3(grid2), dim3(WPB * 64), 0,
                           stream, hs, table, out, BT, D4);
        break;
      default:
        hipLaunchKernelGGL(seg_mean_kernel<4>, dim3(grid2), dim3(WPB * 64), 0,
                           stream, hs, table, out, BT, D4);
        break;
    }
  } else {
    hipLaunchKernelGGL(seg_mean_fallback, dim3(BT), dim3(256), 0, stream,
                       hs, table, out, D);
  }
}